// Round 1
// baseline (1023.770 us; speedup 1.0000x reference)
//
#include <hip/hip_runtime.h>
#include <math.h>

// Problem dims
#define BB 16384
#define II 512
#define HH 512
#define G4 2048    // 4*H
#define KD 1024    // I + H

__device__ __forceinline__ float sigm(float v) { return 1.0f / (1.0f + expf(-v)); }

// ---------------- prepass: reorder weights ----------------
// Wg[k][n] with n = h*4 + g  (g = torch gate order i,f,g,o), k in [0,1024)
//   k<512 -> W_ih[g*512+h][k] ; else W_hh[g*512+h][k-512]
// bg[n] = b_ih[g*512+h] + b_hh[g*512+h]
__global__ void k_prep_wg(const float* __restrict__ W_ih, const float* __restrict__ W_hh,
                          const float* __restrict__ b_ih, const float* __restrict__ b_hh,
                          float* __restrict__ Wg, float* __restrict__ bg)
{
    int id = blockIdx.x * 256 + threadIdx.x;   // over 1024*2048
    int n = id & 2047, k = id >> 11;
    int g = n & 3, h = n >> 2;
    float v = (k < 512) ? W_ih[(size_t)(g * 512 + h) * 512 + k]
                        : W_hh[(size_t)(g * 512 + h) * 512 + (k - 512)];
    Wg[(size_t)k * 2048 + n] = v;
    if (k == 0) bg[n] = b_ih[g * 512 + h] + b_hh[g * 512 + h];
}

// Wstk[k][n], n in [0,512): n<256 -> sp/sc path, n>=256 -> tp path (zeros for k>=512)
__global__ void k_prep_ws(const float* __restrict__ W_sp, const float* __restrict__ W_sc,
                          const float* __restrict__ W_tp,
                          const float* __restrict__ b_sp, const float* __restrict__ b_sc,
                          const float* __restrict__ b_tp,
                          float* __restrict__ Wstk, float* __restrict__ bs)
{
    int id = blockIdx.x * 256 + threadIdx.x;   // over 1024*512
    int n = id & 511, k = id >> 9;
    float v;
    if (n < 256) v = (k < 512) ? W_sp[(size_t)n * 512 + k] : W_sc[(size_t)n * 512 + (k - 512)];
    else         v = (k < 512) ? W_tp[(size_t)(n - 256) * 512 + k] : 0.0f;
    Wstk[(size_t)k * 512 + n] = v;
    if (k == 0) bs[n] = (n < 256) ? (b_sp[n] + b_sc[n]) : b_tp[n - 256];
}

// ---------------- GEMM1: gates + fused LSTM elementwise ----------------
// C[16384,2048] = [x|h0] @ Wg + bg ; epilogue computes c1,h1 -> outC,outH
__global__ __launch_bounds__(256) void k_gates(
    const float* __restrict__ x, const float* __restrict__ h0,
    const float* __restrict__ c0,
    const float* __restrict__ Wg, const float* __restrict__ bg,
    float* __restrict__ outH, float* __restrict__ outC)
{
    __shared__ float As[16][132];
    __shared__ float Bs[16][132];
    const int bid = blockIdx.x;
    const int bm = (bid >> 4) << 7;   // 128 row tiles
    const int bn = (bid & 15) << 7;   // 16 col tiles of 128
    const int tid = threadIdx.x;
    const int tx = tid & 15, ty = tid >> 4;

    float acc[8][8];
    {
        float bias[8];
#pragma unroll
        for (int j = 0; j < 4; ++j) {
            bias[j]     = bg[bn + tx * 4 + j];
            bias[4 + j] = bg[bn + 64 + tx * 4 + j];
        }
#pragma unroll
        for (int i = 0; i < 8; ++i)
#pragma unroll
            for (int j = 0; j < 8; ++j) acc[i][j] = bias[j];
    }

    const int lrow = tid >> 2;          // 0..63
    const int lc4  = (tid & 3) << 2;    // 0,4,8,12

    for (int bk = 0; bk < KD; bk += 16) {
        const float* Asrc = (bk < 512) ? (x + bk) : (h0 + (bk - 512));
#pragma unroll
        for (int rr = 0; rr < 128; rr += 64) {
            float4 v = *(const float4*)(Asrc + (size_t)(bm + lrow + rr) * 512 + lc4);
            As[lc4 + 0][lrow + rr] = v.x;
            As[lc4 + 1][lrow + rr] = v.y;
            As[lc4 + 2][lrow + rr] = v.z;
            As[lc4 + 3][lrow + rr] = v.w;
        }
#pragma unroll
        for (int it = 0; it < 2; ++it) {
            int idx = tid + it * 256;
            int r = idx >> 5, c4 = (idx & 31) << 2;
            *(float4*)&Bs[r][c4] = *(const float4*)(Wg + (size_t)(bk + r) * 2048 + bn + c4);
        }
        __syncthreads();
#pragma unroll
        for (int k = 0; k < 16; ++k) {
            float4 a0 = *(const float4*)&As[k][ty * 4];
            float4 a1 = *(const float4*)&As[k][64 + ty * 4];
            float4 b0 = *(const float4*)&Bs[k][tx * 4];
            float4 b1 = *(const float4*)&Bs[k][64 + tx * 4];
            float av[8] = {a0.x, a0.y, a0.z, a0.w, a1.x, a1.y, a1.z, a1.w};
            float bv[8] = {b0.x, b0.y, b0.z, b0.w, b1.x, b1.y, b1.z, b1.w};
#pragma unroll
            for (int i = 0; i < 8; ++i)
#pragma unroll
                for (int j = 0; j < 8; ++j)
                    acc[i][j] = fmaf(av[i], bv[j], acc[i][j]);
        }
        __syncthreads();
    }

    // epilogue: each 4-col group = one h's 4 gates (i,f,g,o)
#pragma unroll
    for (int i = 0; i < 8; ++i) {
        int row = bm + ((i < 4) ? (ty * 4 + i) : (64 + ty * 4 + (i - 4)));
#pragma unroll
        for (int hh = 0; hh < 2; ++hh) {
            int h = (bn >> 2) + tx + hh * 16;
            float ig = sigm(acc[i][hh * 4 + 0]);
            float fg = sigm(acc[i][hh * 4 + 1]);
            float gg = tanhf(acc[i][hh * 4 + 2]);
            float og = sigm(acc[i][hh * 4 + 3]);
            size_t idx = (size_t)row * 512 + h;
            float c1 = fg * c0[idx] + ig * gg;
            float h1 = og * tanhf(c1);
            outC[idx] = c1;
            outH[idx] = h1;
        }
    }
}

// ---------------- GEMM2: sg|tg = lrelu([c0|c1] @ Wstk + bs) ----------------
__global__ __launch_bounds__(256) void k_sgtg(
    const float* __restrict__ c0, const float* __restrict__ c1,
    const float* __restrict__ Wstk, const float* __restrict__ bs,
    float* __restrict__ sgtg)
{
    __shared__ float As[16][132];
    __shared__ float Bs[16][132];
    const int bid = blockIdx.x;
    const int bm = (bid >> 2) << 7;   // 128 row tiles
    const int bn = (bid & 3) << 7;    // 4 col tiles of 128
    const int tid = threadIdx.x;
    const int tx = tid & 15, ty = tid >> 4;

    float acc[8][8];
    {
        float bias[8];
#pragma unroll
        for (int j = 0; j < 4; ++j) {
            bias[j]     = bs[bn + tx * 4 + j];
            bias[4 + j] = bs[bn + 64 + tx * 4 + j];
        }
#pragma unroll
        for (int i = 0; i < 8; ++i)
#pragma unroll
            for (int j = 0; j < 8; ++j) acc[i][j] = bias[j];
    }

    const int lrow = tid >> 2;
    const int lc4  = (tid & 3) << 2;

    for (int bk = 0; bk < KD; bk += 16) {
        const float* Asrc = (bk < 512) ? (c0 + bk) : (c1 + (bk - 512));
#pragma unroll
        for (int rr = 0; rr < 128; rr += 64) {
            float4 v = *(const float4*)(Asrc + (size_t)(bm + lrow + rr) * 512 + lc4);
            As[lc4 + 0][lrow + rr] = v.x;
            As[lc4 + 1][lrow + rr] = v.y;
            As[lc4 + 2][lrow + rr] = v.z;
            As[lc4 + 3][lrow + rr] = v.w;
        }
#pragma unroll
        for (int it = 0; it < 2; ++it) {
            int idx = tid + it * 256;
            int r = idx >> 5, c4 = (idx & 31) << 2;
            *(float4*)&Bs[r][c4] = *(const float4*)(Wstk + (size_t)(bk + r) * 512 + bn + c4);
        }
        __syncthreads();
#pragma unroll
        for (int k = 0; k < 16; ++k) {
            float4 a0 = *(const float4*)&As[k][ty * 4];
            float4 a1 = *(const float4*)&As[k][64 + ty * 4];
            float4 b0 = *(const float4*)&Bs[k][tx * 4];
            float4 b1 = *(const float4*)&Bs[k][64 + tx * 4];
            float av[8] = {a0.x, a0.y, a0.z, a0.w, a1.x, a1.y, a1.z, a1.w};
            float bv[8] = {b0.x, b0.y, b0.z, b0.w, b1.x, b1.y, b1.z, b1.w};
#pragma unroll
            for (int i = 0; i < 8; ++i)
#pragma unroll
                for (int j = 0; j < 8; ++j)
                    acc[i][j] = fmaf(av[i], bv[j], acc[i][j]);
        }
        __syncthreads();
    }

#pragma unroll
    for (int i = 0; i < 8; ++i) {
        int row = bm + ((i < 4) ? (ty * 4 + i) : (64 + ty * 4 + (i - 4)));
#pragma unroll
        for (int hh = 0; hh < 2; ++hh) {
            float4 v;
            v.x = acc[i][hh * 4 + 0]; v.y = acc[i][hh * 4 + 1];
            v.z = acc[i][hh * 4 + 2]; v.w = acc[i][hh * 4 + 3];
            v.x = v.x > 0.f ? v.x : 0.01f * v.x;
            v.y = v.y > 0.f ? v.y : 0.01f * v.y;
            v.z = v.z > 0.f ? v.z : 0.01f * v.z;
            v.w = v.w > 0.f ? v.w : 0.01f * v.w;
            *(float4*)&sgtg[(size_t)row * 512 + bn + hh * 64 + tx * 4] = v;
        }
    }
}

// ---------------- final: row dots, threshold decision, gated writeback ----------------
__global__ __launch_bounds__(256) void k_final(
    const float* __restrict__ sgtg,
    const float* __restrict__ h0, const float* __restrict__ c0,
    const float* __restrict__ cum,
    const float* __restrict__ W_so, const float* __restrict__ b_so,
    const float* __restrict__ W_to, const float* __restrict__ b_to,
    float* __restrict__ outH, float* __restrict__ outC,
    float* __restrict__ outCum, float* __restrict__ outDelta, float* __restrict__ outProb)
{
    int w = threadIdx.x >> 6;
    int lane = threadIdx.x & 63;
    int b = blockIdx.x * 4 + w;
    const float* row = sgtg + (size_t)b * 512;
    float so = 0.f, to = 0.f;
#pragma unroll
    for (int u = 0; u < 4; ++u) {
        int c = lane + 64 * u;
        so = fmaf(row[c], W_so[c], so);
        to = fmaf(row[256 + c], W_to[c], to);
    }
#pragma unroll
    for (int off = 32; off; off >>= 1) {
        so += __shfl_down(so, off);
        to += __shfl_down(to, off);
    }
    so = __shfl(so, 0);
    to = __shfl(to, 0);
    float delta = sigm(so + b_so[0]);
    float thr   = sigm(to + b_to[0]);
    float cu = cum[b];
    float prob = cu + fminf(delta, 1.0f - cu);
    float hard = (prob > thr) ? 1.0f : 0.0f;
    if (lane == 0) {
        outDelta[b] = delta;
        outProb[b]  = prob;
        outCum[b]   = (1.0f - hard) * prob;
    }
    if (hard == 0.0f) {   // row keeps old state: overwrite staged h1/c1
#pragma unroll
        for (int u = 0; u < 8; ++u) {
            size_t idx = (size_t)b * 512 + lane + 64 * u;
            outH[idx] = h0[idx];
            outC[idx] = c0[idx];
        }
    }
}

extern "C" void kernel_launch(void* const* d_in, const int* in_sizes, int n_in,
                              void* d_out, int out_size, void* d_ws, size_t ws_size,
                              hipStream_t stream)
{
    const float* x    = (const float*)d_in[0];
    const float* h0   = (const float*)d_in[1];
    const float* c0   = (const float*)d_in[2];
    const float* cum  = (const float*)d_in[3];
    const float* W_ih = (const float*)d_in[4];
    const float* W_hh = (const float*)d_in[5];
    const float* b_ih = (const float*)d_in[6];
    const float* b_hh = (const float*)d_in[7];
    const float* W_sp = (const float*)d_in[8];
    const float* b_sp = (const float*)d_in[9];
    const float* W_sc = (const float*)d_in[10];
    const float* b_sc = (const float*)d_in[11];
    const float* W_so = (const float*)d_in[12];
    const float* b_so = (const float*)d_in[13];
    const float* W_tp = (const float*)d_in[14];
    const float* b_tp = (const float*)d_in[15];
    const float* W_to = (const float*)d_in[16];
    const float* b_to = (const float*)d_in[17];

    float* out      = (float*)d_out;
    float* outH     = out;
    float* outC     = out + (size_t)BB * HH;
    float* outCum   = out + (size_t)2 * BB * HH;
    float* outDelta = outCum + BB;
    float* outProb  = outDelta + BB;

    float* ws   = (float*)d_ws;
    float* Wg   = ws;                              // 1024*2048
    float* bg   = Wg + (size_t)1024 * 2048;        // 2048
    float* Wstk = bg + 2048;                       // 1024*512
    float* bs   = Wstk + (size_t)1024 * 512;       // 512
    float* sgtg = bs + 512;                        // 16384*512

    k_prep_wg<<<8192, 256, 0, stream>>>(W_ih, W_hh, b_ih, b_hh, Wg, bg);
    k_prep_ws<<<2048, 256, 0, stream>>>(W_sp, W_sc, W_tp, b_sp, b_sc, b_tp, Wstk, bs);
    k_gates<<<2048, 256, 0, stream>>>(x, h0, c0, Wg, bg, outH, outC);
    k_sgtg<<<512, 256, 0, stream>>>(c0, outC, Wstk, bs, sgtg);
    k_final<<<4096, 256, 0, stream>>>(sgtg, h0, c0, cum, W_so, b_so, W_to, b_to,
                                      outH, outC, outCum, outDelta, outProb);
}

// Round 2
// 343.889 us; speedup vs baseline: 2.9770x; 2.9770x over previous
//
#include <hip/hip_runtime.h>
#include <math.h>

#define BB 16384
#define HH 512

typedef short short8 __attribute__((ext_vector_type(8)));
typedef float f32x4 __attribute__((ext_vector_type(4)));
typedef unsigned short ushort_t;

__device__ __forceinline__ float sigm(float v){ return 1.0f/(1.0f+expf(-v)); }

__device__ __forceinline__ unsigned short f2bf(float f){
    unsigned int u = __float_as_uint(f);
    u = u + 0x7FFFu + ((u>>16)&1u);
    return (unsigned short)(u>>16);
}
__device__ __forceinline__ float bf2f(unsigned short h){
    return __uint_as_float(((unsigned int)h)<<16);
}
__device__ __forceinline__ void gll16(const void* g, void* l){
    __builtin_amdgcn_global_load_lds((const __attribute__((address_space(1))) void*)g,
                                     (__attribute__((address_space(3))) void*)l, 16, 0, 0);
}

// ---------- prepass: A1 = [x|h0] -> bf16 hi/lo, tiled chunk-major ----------
// tile(tm,tk): 128 rows x 32 k, layout [c=k/8 (4)][r (128)][j (8)] ; tiles k-major per tm
__global__ void k_prep_A(const float* __restrict__ x, const float* __restrict__ h0,
                         ushort_t* __restrict__ A1h, ushort_t* __restrict__ A1l)
{
    int u = blockIdx.x*256 + threadIdx.x;      // 2,097,152 units of 8 elems
    int r  = u & 127;
    int c  = (u >> 7) & 3;
    int tk = (u >> 9) & 31;
    int tm = u >> 14;
    int row = tm*128 + r;
    int k0 = tk*32 + c*8;
    const float* src = (k0 < 512) ? (x + (size_t)row*512 + k0)
                                  : (h0 + (size_t)row*512 + (k0-512));
    float4 v0 = *(const float4*)(src);
    float4 v1 = *(const float4*)(src+4);
    float vv[8] = {v0.x,v0.y,v0.z,v0.w,v1.x,v1.y,v1.z,v1.w};
    short8 hi, lo;
#pragma unroll
    for (int j=0;j<8;++j){
        unsigned short h = f2bf(vv[j]);
        unsigned short l = f2bf(vv[j] - bf2f(h));
        hi[j] = (short)h; lo[j] = (short)l;
    }
    size_t off = (size_t)u * 8;
    *(short8*)(A1h + off) = hi;
    *(short8*)(A1l + off) = lo;
}

// ---------- prepass: A2 low half (c0), tiles tk 0..15 ----------
__global__ void k_prep_A2(const float* __restrict__ c0,
                          ushort_t* __restrict__ A2h, ushort_t* __restrict__ A2l)
{
    int u = blockIdx.x*256 + threadIdx.x;      // 1,048,576
    int r  = u & 127;
    int c  = (u >> 7) & 3;
    int tk = (u >> 9) & 15;
    int tm = u >> 13;
    int row = tm*128 + r;
    int k0 = tk*32 + c*8;
    const float* src = c0 + (size_t)row*512 + k0;
    float4 v0 = *(const float4*)(src);
    float4 v1 = *(const float4*)(src+4);
    float vv[8] = {v0.x,v0.y,v0.z,v0.w,v1.x,v1.y,v1.z,v1.w};
    short8 hi, lo;
#pragma unroll
    for (int j=0;j<8;++j){
        unsigned short h = f2bf(vv[j]);
        unsigned short l = f2bf(vv[j] - bf2f(h));
        hi[j] = (short)h; lo[j] = (short)l;
    }
    size_t off = ((size_t)tm*32 + tk)*4096 + (size_t)(c*128 + r)*8;
    *(short8*)(A2h + off) = hi;
    *(short8*)(A2l + off) = lo;
}

// ---------- prepass: B1 (gates weights), gate-permuted n, tiled ----------
// tile row r: wc=r>>6, gate g=(r>>4)&3, h16=r&15 -> h = tn*32 + wc*16 + h16
__global__ void k_prep_B(const float* __restrict__ W_ih, const float* __restrict__ W_hh,
                         const float* __restrict__ b_ih, const float* __restrict__ b_hh,
                         ushort_t* __restrict__ B1h, ushort_t* __restrict__ B1l,
                         float* __restrict__ bgp)
{
    int u = blockIdx.x*256 + threadIdx.x;      // 262,144
    int r  = u & 127;
    int c  = (u >> 7) & 3;
    int tk = (u >> 9) & 31;
    int tn = u >> 14;
    int wcp = r>>6, g=(r>>4)&3, h16 = r&15;
    int h = tn*32 + wcp*16 + h16;
    int wrow = g*512 + h;
    int k0 = tk*32 + c*8;
    const float* src = (k0 < 512) ? (W_ih + (size_t)wrow*512 + k0)
                                  : (W_hh + (size_t)wrow*512 + (k0-512));
    float4 v0 = *(const float4*)(src);
    float4 v1 = *(const float4*)(src+4);
    float vv[8] = {v0.x,v0.y,v0.z,v0.w,v1.x,v1.y,v1.z,v1.w};
    short8 hi, lo;
#pragma unroll
    for (int j=0;j<8;++j){
        unsigned short hq = f2bf(vv[j]);
        unsigned short lq = f2bf(vv[j] - bf2f(hq));
        hi[j] = (short)hq; lo[j] = (short)lq;
    }
    size_t off = (size_t)u * 8;
    *(short8*)(B1h + off) = hi;
    *(short8*)(B1l + off) = lo;
    if (tk == 0 && c == 0) bgp[tn*128 + r] = b_ih[wrow] + b_hh[wrow];
}

// ---------- prepass: B2 (skip/threshold weights), natural n, tiled ----------
__global__ void k_prep_B2(const float* __restrict__ W_sp, const float* __restrict__ W_sc,
                          const float* __restrict__ W_tp,
                          const float* __restrict__ b_sp, const float* __restrict__ b_sc,
                          const float* __restrict__ b_tp,
                          ushort_t* __restrict__ B2h, ushort_t* __restrict__ B2l,
                          float* __restrict__ bs2)
{
    int u = blockIdx.x*256 + threadIdx.x;      // 65,536
    int r  = u & 127;
    int c  = (u >> 7) & 3;
    int tk = (u >> 9) & 31;
    int tn = u >> 14;
    int n = tn*128 + r;
    int k0 = tk*32 + c*8;
    float vv[8];
    if (n < 256) {
        const float* src = (k0 < 512) ? (W_sp + (size_t)n*512 + k0)
                                      : (W_sc + (size_t)n*512 + (k0-512));
        float4 v0 = *(const float4*)(src);
        float4 v1 = *(const float4*)(src+4);
        vv[0]=v0.x; vv[1]=v0.y; vv[2]=v0.z; vv[3]=v0.w;
        vv[4]=v1.x; vv[5]=v1.y; vv[6]=v1.z; vv[7]=v1.w;
    } else if (k0 < 512) {
        const float* src = W_tp + (size_t)(n-256)*512 + k0;
        float4 v0 = *(const float4*)(src);
        float4 v1 = *(const float4*)(src+4);
        vv[0]=v0.x; vv[1]=v0.y; vv[2]=v0.z; vv[3]=v0.w;
        vv[4]=v1.x; vv[5]=v1.y; vv[6]=v1.z; vv[7]=v1.w;
    } else {
#pragma unroll
        for (int j=0;j<8;++j) vv[j] = 0.0f;
    }
    short8 hi, lo;
#pragma unroll
    for (int j=0;j<8;++j){
        unsigned short hq = f2bf(vv[j]);
        unsigned short lq = f2bf(vv[j] - bf2f(hq));
        hi[j] = (short)hq; lo[j] = (short)lq;
    }
    size_t off = (size_t)u * 8;
    *(short8*)(B2h + off) = hi;
    *(short8*)(B2l + off) = lo;
    if (tk == 0 && c == 0) bs2[n] = (n < 256) ? (b_sp[n] + b_sc[n]) : b_tp[n-256];
}

// ---------- GEMM1: gates (split bf16 MFMA) + fused LSTM epilogue ----------
__global__ __launch_bounds__(256) void k_gemm_gates(
    const ushort_t* __restrict__ Ah, const ushort_t* __restrict__ Al,
    const ushort_t* __restrict__ Bh, const ushort_t* __restrict__ Bl,
    const float* __restrict__ bgp, const float* __restrict__ c0,
    float* __restrict__ outH, float* __restrict__ outC,
    ushort_t* __restrict__ A2h, ushort_t* __restrict__ A2l)
{
    __shared__ __align__(16) ushort_t AsH[4096];
    __shared__ __align__(16) ushort_t AsL[4096];
    __shared__ __align__(16) ushort_t BsH[4096];
    __shared__ __align__(16) ushort_t BsL[4096];
    const int tid = threadIdx.x;
    const int lane = tid & 63;
    const int wid = tid >> 6;
    const int wr = wid >> 1, wc = wid & 1;
    const int bid = (int)blockIdx.x;
    const int v = (bid & 7)*256 + (bid >> 3);   // XCD swizzle (2048 % 8 == 0)
    const int tm = v >> 4;
    const int tn = v & 15;
    const int l15 = lane & 15;
    const int lq = lane >> 4;

    f32x4 acc[4][4];
#pragma unroll
    for (int fn = 0; fn < 4; ++fn) {
        float bv = bgp[tn*128 + wc*64 + fn*16 + l15];
#pragma unroll
        for (int fm = 0; fm < 4; ++fm) {
            acc[fm][fn][0]=bv; acc[fm][fn][1]=bv; acc[fm][fn][2]=bv; acc[fm][fn][3]=bv;
        }
    }

    const size_t baseA = (size_t)tm * (32*4096);
    const size_t baseB = (size_t)tn * (32*4096);
    int aoff[4], boff[4];
#pragma unroll
    for (int f = 0; f < 4; ++f) {
        aoff[f] = (lq*128 + wr*64 + f*16 + l15) * 8;
        boff[f] = (lq*128 + wc*64 + f*16 + l15) * 8;
    }
    const int si = wid * 2;

    for (int tk = 0; tk < 32; ++tk) {
        size_t ga = baseA + (size_t)tk*4096 + (size_t)lane*8;
        size_t gb = baseB + (size_t)tk*4096 + (size_t)lane*8;
#pragma unroll
        for (int t = 0; t < 2; ++t) {
            int i = si + t;
            gll16(Ah + ga + i*512, AsH + i*512);
            gll16(Al + ga + i*512, AsL + i*512);
            gll16(Bh + gb + i*512, BsH + i*512);
            gll16(Bl + gb + i*512, BsL + i*512);
        }
        __syncthreads();
        short8 bhv[4], blv[4];
#pragma unroll
        for (int fn = 0; fn < 4; ++fn) {
            bhv[fn] = *(const short8*)&BsH[boff[fn]];
            blv[fn] = *(const short8*)&BsL[boff[fn]];
        }
#pragma unroll
        for (int fm = 0; fm < 4; ++fm) {
            short8 ahv = *(const short8*)&AsH[aoff[fm]];
            short8 alv = *(const short8*)&AsL[aoff[fm]];
#pragma unroll
            for (int fn = 0; fn < 4; ++fn) {
                acc[fm][fn] = __builtin_amdgcn_mfma_f32_16x16x32_bf16(ahv, bhv[fn], acc[fm][fn], 0,0,0);
                acc[fm][fn] = __builtin_amdgcn_mfma_f32_16x16x32_bf16(alv, bhv[fn], acc[fm][fn], 0,0,0);
                acc[fm][fn] = __builtin_amdgcn_mfma_f32_16x16x32_bf16(ahv, blv[fn], acc[fm][fn], 0,0,0);
            }
        }
        __syncthreads();
    }

    // epilogue: lane holds all 4 gates (fn=gate) for rows (lq*4+r), col h
    const int hb = tn*32 + wc*16;
    const int h = hb + l15;
#pragma unroll
    for (int fm = 0; fm < 4; ++fm) {
        int row0 = tm*128 + wr*64 + fm*16 + lq*4;
#pragma unroll
        for (int r = 0; r < 4; ++r) {
            int row = row0 + r;
            size_t idx = (size_t)row*512 + h;
            float ig = sigm(acc[fm][0][r]);
            float fg = sigm(acc[fm][1][r]);
            float gg = tanhf(acc[fm][2][r]);
            float og = sigm(acc[fm][3][r]);
            float c1 = fg*c0[idx] + ig*gg;
            float h1 = og*tanhf(c1);
            outC[idx] = c1;
            outH[idx] = h1;
            unsigned short ch = f2bf(c1);
            unsigned short cl = f2bf(c1 - bf2f(ch));
            size_t a2 = ((size_t)tm*32 + 16 + tn)*4096
                      + (size_t)((wc*2 + (l15>>3))*128 + (row & 127))*8 + (l15 & 7);
            A2h[a2] = ch;
            A2l[a2] = cl;
        }
    }
}

// ---------- GEMM2: sg|tg = lrelu([c0|c1] @ B2 + bs2) ----------
__global__ __launch_bounds__(256) void k_gemm_sgtg(
    const ushort_t* __restrict__ Ah, const ushort_t* __restrict__ Al,
    const ushort_t* __restrict__ Bh, const ushort_t* __restrict__ Bl,
    const float* __restrict__ bs2,
    float* __restrict__ sgtg)
{
    __shared__ __align__(16) ushort_t AsH[4096];
    __shared__ __align__(16) ushort_t AsL[4096];
    __shared__ __align__(16) ushort_t BsH[4096];
    __shared__ __align__(16) ushort_t BsL[4096];
    const int tid = threadIdx.x;
    const int lane = tid & 63;
    const int wid = tid >> 6;
    const int wr = wid >> 1, wc = wid & 1;
    const int bid = (int)blockIdx.x;
    const int v = (bid & 7)*64 + (bid >> 3);    // XCD swizzle (512 % 8 == 0)
    const int tm = v >> 2;
    const int tn = v & 3;
    const int l15 = lane & 15;
    const int lq = lane >> 4;

    f32x4 acc[4][4];
#pragma unroll
    for (int fn = 0; fn < 4; ++fn) {
        float bv = bs2[tn*128 + wc*64 + fn*16 + l15];
#pragma unroll
        for (int fm = 0; fm < 4; ++fm) {
            acc[fm][fn][0]=bv; acc[fm][fn][1]=bv; acc[fm][fn][2]=bv; acc[fm][fn][3]=bv;
        }
    }

    const size_t baseA = (size_t)tm * (32*4096);
    const size_t baseB = (size_t)tn * (32*4096);
    int aoff[4], boff[4];
#pragma unroll
    for (int f = 0; f < 4; ++f) {
        aoff[f] = (lq*128 + wr*64 + f*16 + l15) * 8;
        boff[f] = (lq*128 + wc*64 + f*16 + l15) * 8;
    }
    const int si = wid * 2;

    for (int tk = 0; tk < 32; ++tk) {
        size_t ga = baseA + (size_t)tk*4096 + (size_t)lane*8;
        size_t gb = baseB + (size_t)tk*4096 + (size_t)lane*8;
#pragma unroll
        for (int t = 0; t < 2; ++t) {
            int i = si + t;
            gll16(Ah + ga + i*512, AsH + i*512);
            gll16(Al + ga + i*512, AsL + i*512);
            gll16(Bh + gb + i*512, BsH + i*512);
            gll16(Bl + gb + i*512, BsL + i*512);
        }
        __syncthreads();
        short8 bhv[4], blv[4];
#pragma unroll
        for (int fn = 0; fn < 4; ++fn) {
            bhv[fn] = *(const short8*)&BsH[boff[fn]];
            blv[fn] = *(const short8*)&BsL[boff[fn]];
        }
#pragma unroll
        for (int fm = 0; fm < 4; ++fm) {
            short8 ahv = *(const short8*)&AsH[aoff[fm]];
            short8 alv = *(const short8*)&AsL[aoff[fm]];
#pragma unroll
            for (int fn = 0; fn < 4; ++fn) {
                acc[fm][fn] = __builtin_amdgcn_mfma_f32_16x16x32_bf16(ahv, bhv[fn], acc[fm][fn], 0,0,0);
                acc[fm][fn] = __builtin_amdgcn_mfma_f32_16x16x32_bf16(alv, bhv[fn], acc[fm][fn], 0,0,0);
                acc[fm][fn] = __builtin_amdgcn_mfma_f32_16x16x32_bf16(ahv, blv[fn], acc[fm][fn], 0,0,0);
            }
        }
        __syncthreads();
    }

#pragma unroll
    for (int fm = 0; fm < 4; ++fm) {
        int row0 = tm*128 + wr*64 + fm*16 + lq*4;
#pragma unroll
        for (int fn = 0; fn < 4; ++fn) {
            int n = tn*128 + wc*64 + fn*16 + l15;
#pragma unroll
            for (int r = 0; r < 4; ++r) {
                int row = row0 + r;
                float vv = acc[fm][fn][r];
                vv = vv > 0.f ? vv : 0.01f*vv;
                sgtg[(size_t)row*512 + n] = vv;
            }
        }
    }
}

// ---------- final: row dots, threshold decision, gated writeback ----------
__global__ __launch_bounds__(256) void k_final(
    const float* __restrict__ sgtg,
    const float* __restrict__ h0, const float* __restrict__ c0,
    const float* __restrict__ cum,
    const float* __restrict__ W_so, const float* __restrict__ b_so,
    const float* __restrict__ W_to, const float* __restrict__ b_to,
    float* __restrict__ outH, float* __restrict__ outC,
    float* __restrict__ outCum, float* __restrict__ outDelta, float* __restrict__ outProb)
{
    int w = threadIdx.x >> 6;
    int lane = threadIdx.x & 63;
    int b = blockIdx.x * 4 + w;
    const float* row = sgtg + (size_t)b * 512;
    float so = 0.f, to = 0.f;
#pragma unroll
    for (int u = 0; u < 4; ++u) {
        int c = lane + 64 * u;
        so = fmaf(row[c], W_so[c], so);
        to = fmaf(row[256 + c], W_to[c], to);
    }
#pragma unroll
    for (int off = 32; off; off >>= 1) {
        so += __shfl_down(so, off);
        to += __shfl_down(to, off);
    }
    so = __shfl(so, 0);
    to = __shfl(to, 0);
    float delta = sigm(so + b_so[0]);
    float thr   = sigm(to + b_to[0]);
    float cu = cum[b];
    float prob = cu + fminf(delta, 1.0f - cu);
    float hard = (prob > thr) ? 1.0f : 0.0f;
    if (lane == 0) {
        outDelta[b] = delta;
        outProb[b]  = prob;
        outCum[b]   = (1.0f - hard) * prob;
    }
    if (hard == 0.0f) {
#pragma unroll
        for (int u = 0; u < 8; ++u) {
            size_t idx = (size_t)b * 512 + lane + 64 * u;
            outH[idx] = h0[idx];
            outC[idx] = c0[idx];
        }
    }
}

extern "C" void kernel_launch(void* const* d_in, const int* in_sizes, int n_in,
                              void* d_out, int out_size, void* d_ws, size_t ws_size,
                              hipStream_t stream)
{
    const float* x    = (const float*)d_in[0];
    const float* h0   = (const float*)d_in[1];
    const float* c0   = (const float*)d_in[2];
    const float* cum  = (const float*)d_in[3];
    const float* W_ih = (const float*)d_in[4];
    const float* W_hh = (const float*)d_in[5];
    const float* b_ih = (const float*)d_in[6];
    const float* b_hh = (const float*)d_in[7];
    const float* W_sp = (const float*)d_in[8];
    const float* b_sp = (const float*)d_in[9];
    const float* W_sc = (const float*)d_in[10];
    const float* b_sc = (const float*)d_in[11];
    const float* W_so = (const float*)d_in[12];
    const float* b_so = (const float*)d_in[13];
    const float* W_tp = (const float*)d_in[14];
    const float* b_tp = (const float*)d_in[15];
    const float* W_to = (const float*)d_in[16];
    const float* b_to = (const float*)d_in[17];

    float* out      = (float*)d_out;
    float* outH     = out;
    float* outC     = out + (size_t)BB * HH;
    float* outCum   = out + (size_t)2 * BB * HH;
    float* outDelta = outCum + BB;
    float* outProb  = outDelta + BB;

    char* w = (char*)d_ws;
    ushort_t* A1h = (ushort_t*)(w);                       // 33,554,432 B
    ushort_t* A1l = (ushort_t*)(w + 33554432ull);         // 33,554,432 B
    ushort_t* A2h = (ushort_t*)(w + 67108864ull);         // 33,554,432 B
    ushort_t* A2l = (ushort_t*)(w + 100663296ull);        // 33,554,432 B
    ushort_t* B1h = (ushort_t*)(w + 134217728ull);        //  4,194,304 B
    ushort_t* B1l = (ushort_t*)(w + 138412032ull);        //  4,194,304 B
    ushort_t* B2h = (ushort_t*)(w + 142606336ull);        //  1,048,576 B
    ushort_t* B2l = (ushort_t*)(w + 143654912ull);        //  1,048,576 B
    float*    bgp = (float*)(w + 144703488ull);           //      8,192 B
    float*    bs2 = (float*)(w + 144711680ull);           //      2,048 B
    float*    sgtg = (float*)A1h;   // alias: A1 dead after k_gemm_gates

    k_prep_A <<<8192, 256, 0, stream>>>(x, h0, A1h, A1l);
    k_prep_A2<<<4096, 256, 0, stream>>>(c0, A2h, A2l);
    k_prep_B <<<1024, 256, 0, stream>>>(W_ih, W_hh, b_ih, b_hh, B1h, B1l, bgp);
    k_prep_B2<<<256, 256, 0, stream>>>(W_sp, W_sc, W_tp, b_sp, b_sc, b_tp, B2h, B2l, bs2);
    k_gemm_gates<<<2048, 256, 0, stream>>>(A1h, A1l, B1h, B1l, bgp, c0,
                                           outH, outC, A2h, A2l);
    k_gemm_sgtg<<<512, 256, 0, stream>>>(A2h, A2l, B2h, B2l, bs2, sgtg);
    k_final<<<4096, 256, 0, stream>>>(sgtg, h0, c0, cum, W_so, b_so, W_to, b_to,
                                      outH, outC, outCum, outDelta, outProb);
}